// Round 8
// baseline (91.913 us; speedup 1.0000x reference)
//
#include <hip/hip_runtime.h>
#include <hip/hip_bf16.h>

// Problem constants
#define BB 32
#define SS 256
#define DD 300
#define PDD 32
#define MM 66
#define FF 398      // D + PD + M
#define HH 6
#define G4 24       // 4*H
#define AA 12
#define L2E 1.4426950408889634f

__device__ __forceinline__ float fast_rcp(float x) { return __builtin_amdgcn_rcpf(x); }
__device__ __forceinline__ float fast_tanh(float x) {
    return 1.f - 2.f * fast_rcp(__expf(2.f * x) + 1.f);
}
__device__ __forceinline__ float bcast_lane(float x, int l) {
    return __int_as_float(__builtin_amdgcn_readlane(__float_as_int(x), l));
}
template<int CTRL>
__device__ __forceinline__ float quad_bcast(float v) {
    // DPP quad_perm broadcast: CTRL = 0 / 85 / 170 / 255 -> quad lane 0/1/2/3
    return __int_as_float(__builtin_amdgcn_mov_dpp(__float_as_int(v), CTRL, 0xf, 0xf, true));
}

// -------------------------------------------------------------------------
// Kernel 1a: gather embeddings/morph into flat padded feats[8192][400] and
// build transposed, padded weight WT[2][24][400]. Pure memory op.
// -------------------------------------------------------------------------
__global__ __launch_bounds__(256) void k_prep(
    const int* __restrict__ words, const int* __restrict__ pos,
    const float* __restrict__ morph, const float* __restrict__ wtab,
    const float* __restrict__ ptab,
    const float* __restrict__ Wxf, const float* __restrict__ Wxb,
    float* __restrict__ feats, float* __restrict__ WT)
{
    int t  = threadIdx.x;
    int pl = t >> 4;                 // 0..15 (position within block)
    int ln = t & 15;
    int p  = blockIdx.x * 16 + pl;

    float* frow = feats + (size_t)p * 400;
    float4* f4  = (float4*)frow;
    // word part: k 0..299 = 75 float4
    const float4* ws4 = (const float4*)(wtab + (size_t)words[p] * DD);
    for (int k4 = ln; k4 < 75; k4 += 16) f4[k4] = ws4[k4];
    // pos part: k 300..331 = 8 float4
    const float4* ps4 = (const float4*)(ptab + pos[p] * PDD);
    if (ln < 8) f4[75 + ln] = ps4[ln];
    // morph: k 332..397 = 33 float2 ; pad k 398..399 = 1 float2
    const float2* ms2 = (const float2*)(morph + (size_t)p * MM);
    float2* f2 = (float2*)frow;
    for (int k2 = ln; k2 < 33; k2 += 16) f2[166 + k2] = ms2[k2];
    if (ln == 0) f2[199] = make_float2(0.f, 0.f);

    // WT[dir][j][k] = Wx_dir[k][j], zero-padded k>=398 (blocks 0,1 only)
    if (blockIdx.x < 2) {
        const float* Wx = blockIdx.x ? Wxb : Wxf;
        float* wt = WT + blockIdx.x * (G4 * 400);
        for (int idx = t; idx < G4 * 400; idx += 256) {
            int jj = idx / 400, k = idx % 400;
            wt[idx] = (k < FF) ? Wx[k * G4 + jj] : 0.f;
        }
    }
}

// -------------------------------------------------------------------------
// Kernel 1b: xg = feats @ Wx + b as a scalar-operand GEMM.
// Wave = 64 positions x one wave-uniform 6-col group (readfirstlane) ->
// W addresses are uniform -> s_load through the scalar pipe, consumed as
// the single-SGPR operand of v_fma_f32. Per q: 1 global b128 (feats,
// per-lane) + 24 fma. No LDS at all.
// -------------------------------------------------------------------------
__global__ __launch_bounds__(256) void k_xg(
    const float* __restrict__ feats, const float* __restrict__ WT,
    const float* __restrict__ bfv, const float* __restrict__ bbv,
    float* __restrict__ xgf, float* __restrict__ xgb)
{
    int tile = blockIdx.x >> 1;
    int half = blockIdx.x & 1;
    int wave = threadIdx.x >> 6;
    int lane = threadIdx.x & 63;
    int cg   = __builtin_amdgcn_readfirstlane(half * 4 + wave);  // 0..7
    int dir  = cg >> 2;
    int j0   = (cg & 3) * 6;
    int pp   = tile * 64 + lane;                  // position 0..8191

    const float4* fp4 = (const float4*)(feats + (size_t)pp * 400);
    const float*  wt0 = WT + dir * (G4 * 400) + j0 * 400;

    float acc[6] = {0.f, 0.f, 0.f, 0.f, 0.f, 0.f};
    #pragma unroll 8
    for (int q = 0; q < 100; ++q) {
        float4 f = fp4[q];
        #pragma unroll
        for (int c2 = 0; c2 < 6; ++c2) {
            const float4 w = *(const float4*)(wt0 + c2 * 400 + q * 4);
            acc[c2] = fmaf(f.x, w.x, acc[c2]);
            acc[c2] = fmaf(f.y, w.y, acc[c2]);
            acc[c2] = fmaf(f.z, w.z, acc[c2]);
            acc[c2] = fmaf(f.w, w.w, acc[c2]);
        }
    }
    const float* bias = dir ? bbv : bfv;
    float2* o2 = (float2*)((dir ? xgb : xgf) + (size_t)pp * G4 + j0);
    o2[0] = make_float2(acc[0] + bias[j0 + 0], acc[1] + bias[j0 + 1]);
    o2[1] = make_float2(acc[2] + bias[j0 + 2], acc[3] + bias[j0 + 3]);
    o2[2] = make_float2(acc[4] + bias[j0 + 4], acc[5] + bias[j0 + 5]);
}

// -------------------------------------------------------------------------
// Kernel 2 (v8): LSTM recurrence, gate-lane layout with DPP quad gathers.
// Lane l owns gate g = l%24, remapped so quad q holds cell q's {i,f,c,o}:
// cell = g>>2, type = g&3, keras col j = type*6+cell. xg and Wh are
// PRE-SCALED by kk (= -log2e for i/f/o, +2log2e for c) so the dot directly
// feeds exp2. Cell update gathers via 4 register-file DPP quad broadcasts
// (replaces the ds_bpermutes' LDS latency). h broadcast via readlane.
// -------------------------------------------------------------------------
__global__ __launch_bounds__(64) void k_lstm(
    const float* __restrict__ xgf, const float* __restrict__ xgb,
    const float* __restrict__ Whf, const float* __restrict__ Whb,
    float* __restrict__ repr)
{
    __shared__ float sxg[(SS + 8) * G4];    // prescaled; 8 zero guard rows
    __shared__ float hbuf[SS * HH];
    int blk = blockIdx.x;                   // 0..63
    int dir = blk >> 5;
    int b   = blk & 31;
    int lane = threadIdx.x;

    const float* xg = (dir ? xgb : xgf) + (size_t)b * SS * G4;
    const float* Wh = dir ? Whb : Whf;

    // stage xg -> LDS: reverse rows for bwd, PRESCALE per keras column
    {
        const float4* src = (const float4*)xg;
        float4* dst = (float4*)sxg;
        #pragma unroll
        for (int u = 0; u < 24; ++u) {
            int d = lane + u * 64;          // float4 index 0..1535
            int row = d / 6, c4 = d - row * 6;
            int drow = dir ? (SS - 1 - row) : row;
            float4 v = src[d];
            int cb = c4 * 4;
            v.x *= (cb + 0 >= 12 && cb + 0 < 18) ? 2.f * L2E : -L2E;
            v.y *= (cb + 1 >= 12 && cb + 1 < 18) ? 2.f * L2E : -L2E;
            v.z *= (cb + 2 >= 12 && cb + 2 < 18) ? 2.f * L2E : -L2E;
            v.w *= (cb + 3 >= 12 && cb + 3 < 18) ? 2.f * L2E : -L2E;
            dst[drow * 6 + c4] = v;
        }
        for (int g2 = lane; g2 < 8 * G4; g2 += 64) sxg[SS * G4 + g2] = 0.f;
    }

    int g    = lane % G4;                   // gate slot 0..23
    int cell = g >> 2;                      // 0..5
    int type = g & 3;                       // 0=i 1=f 2=c 3=o
    int j    = type * HH + cell;            // keras column

    float kk = (type == 2) ? 2.f * L2E : -L2E;
    float wh[HH];
    #pragma unroll
    for (int m = 0; m < HH; ++m) wh[m] = Wh[m * G4 + j] * kk;
    float Bc = (type == 2) ? 1.f : 0.f;
    float Ac = (type == 2) ? -1.f : 1.f;

    float sh[HH];
    #pragma unroll
    for (int m = 0; m < HH; ++m) sh[m] = 0.f;
    float c = 0.f;
    bool wr = (lane < G4) && ((lane & 3) == 0);
    __syncthreads();

    const float* xb = sxg + j;

    // 4-slot rotating register prefetch (1 ds_read per step)
    float pg[4];
    #pragma unroll
    for (int sl = 0; sl < 4; ++sl) pg[sl] = xb[sl * G4];

    #pragma unroll 1
    for (int t = 0; t < SS; t += 4) {
        #pragma unroll
        for (int sl = 0; sl < 4; ++sl) {
            float x = pg[sl];
            pg[sl] = xb[(t + 4 + sl) * G4];      // guard rows cover the tail

            // depth-4 scaled dot: x = kk*(xg_j + sum_m h_m Wh[m][j])
            float aa  = fmaf(sh[1], wh[1], fmaf(sh[0], wh[0], x));
            float bb2 = fmaf(sh[3], wh[3], sh[2] * wh[2]);
            float cc2 = fmaf(sh[5], wh[5], sh[4] * wh[4]);
            x = (aa + bb2) + cc2;

            float e   = __builtin_amdgcn_exp2f(x);
            float val = fmaf(Bc, e, Ac) * fast_rcp(1.f + e);

            // register-file gather of this cell's gates (quad_perm DPP)
            float vi = quad_bcast<0>(val);
            float vf = quad_bcast<85>(val);
            float vc = quad_bcast<170>(val);
            float vo = quad_bcast<255>(val);

            c = fmaf(vf, c, vi * vc);
            float ec = __builtin_amdgcn_exp2f(c * (2.f * L2E));
            float h  = (ec - 1.f) * fast_rcp(ec + 1.f) * vo;

            if (wr) hbuf[(t + sl) * HH + cell] = h;
            #pragma unroll
            for (int m = 0; m < HH; ++m) sh[m] = bcast_lane(h, 4 * m);
        }
    }
    __syncthreads();

    // coalesced copy out (undo time order for bwd)
    #pragma unroll
    for (int u = 0; u < (SS * HH) / 64; ++u) {
        int idx = lane + u * 64;
        int tt = idx / 6, cc = idx - tt * 6;
        int s = dir ? (SS - 1 - tt) : tt;
        repr[((size_t)b * SS + s) * (2 * HH) + dir * HH + cc] = hbuf[idx];
    }
}

// -------------------------------------------------------------------------
// Kernel 3: ua = repr@Wu+bu ; wa = repr@Ww+bw. One thread per (b,s).
// -------------------------------------------------------------------------
__global__ __launch_bounds__(256) void k_uawa(
    const float* __restrict__ repr,
    const float* __restrict__ Wu, const float* __restrict__ bu,
    const float* __restrict__ Ww, const float* __restrict__ bw,
    float* __restrict__ ua, float* __restrict__ wa)
{
    int bs = blockIdx.x * blockDim.x + threadIdx.x;   // 0..8191
    float r[AA];
    #pragma unroll
    for (int e = 0; e < AA; ++e) r[e] = repr[(size_t)bs * AA + e];
    #pragma unroll
    for (int d = 0; d < AA; ++d) {
        float au = bu[d], aw = bw[d];
        #pragma unroll
        for (int e = 0; e < AA; ++e) {
            au = fmaf(r[e], Wu[e * AA + d], au);
            aw = fmaf(r[e], Ww[e * AA + d], aw);
        }
        ua[(size_t)bs * AA + d] = au;
        wa[(size_t)bs * AA + d] = aw;
    }
}

// -------------------------------------------------------------------------
// Kernel 4: arc scores + sum-exp + CE partials + exp table.
// -------------------------------------------------------------------------
__global__ __launch_bounds__(256) void k_score(
    const float* __restrict__ ua, const float* __restrict__ wa,
    const float* __restrict__ v, const int* __restrict__ heads,
    float* __restrict__ out, float* __restrict__ ce)
{
    int bi = blockIdx.x;            // b*S + i
    int i  = bi & 255;
    int j  = threadIdx.x;

    __shared__ float swa[AA], sv[AA];
    if (j < AA) { swa[j] = wa[(size_t)bi * AA + j]; sv[j] = v[j]; }
    __syncthreads();

    const float* uj = ua + ((size_t)(bi & ~255) + j) * AA;
    float s = 0.f;
    #pragma unroll
    for (int d = 0; d < AA; ++d) s = fmaf(sv[d], fast_tanh(uj[d] + swa[d]), s);
    if (j == i) s = -10000.f;

    float e = __expf(s);
    if (i >= 1)
        out[1 + (((size_t)(i - 1) * BB + (bi >> 8)) * SS + j)] = e;

    float r = e;
    #pragma unroll
    for (int off = 32; off > 0; off >>= 1) r += __shfl_xor(r, off, 64);
    __shared__ float part[4];
    if ((j & 63) == 0) part[j >> 6] = r;
    __syncthreads();
    float tot = part[0] + part[1] + part[2] + part[3];

    if (j == heads[bi])
        ce[bi] = (i >= 1) ? (__logf(tot) - s) : 0.f;
}

// -------------------------------------------------------------------------
// Kernel 5: deterministic loss reduction: sum(ce)/B into out[0].
// -------------------------------------------------------------------------
__global__ __launch_bounds__(256) void k_loss(const float* __restrict__ ce,
                                              float* __restrict__ out)
{
    __shared__ float red[256];
    int t = threadIdx.x;
    float a = 0.f;
    for (int k = t; k < BB * SS; k += 256) a += ce[k];
    red[t] = a; __syncthreads();
    for (int off = 128; off > 0; off >>= 1) {
        if (t < off) red[t] += red[t + off];
        __syncthreads();
    }
    if (t == 0) out[0] = red[0] * (1.f / BB);
}

extern "C" void kernel_launch(void* const* d_in, const int* in_sizes, int n_in,
                              void* d_out, int out_size, void* d_ws, size_t ws_size,
                              hipStream_t stream)
{
    const int*   words = (const int*)  d_in[0];
    const int*   pos   = (const int*)  d_in[1];
    const float* morph = (const float*)d_in[2];
    const int*   heads = (const int*)  d_in[3];
    const float* wtab  = (const float*)d_in[4];
    const float* ptab  = (const float*)d_in[5];
    const float* Wxf   = (const float*)d_in[6];
    const float* Whf   = (const float*)d_in[7];
    const float* bf    = (const float*)d_in[8];
    const float* Wxb   = (const float*)d_in[9];
    const float* Whb   = (const float*)d_in[10];
    const float* bb    = (const float*)d_in[11];
    const float* Wu    = (const float*)d_in[12];
    const float* bu    = (const float*)d_in[13];
    const float* Ww    = (const float*)d_in[14];
    const float* bw    = (const float*)d_in[15];
    const float* v     = (const float*)d_in[16];
    float* out = (float*)d_out;

    // workspace layout (floats)
    float* xgf   = (float*)d_ws;                 // 8192*24
    float* xgb   = xgf   + (size_t)BB*SS*G4;     // 8192*24
    float* repr  = xgb   + (size_t)BB*SS*G4;     // 8192*12
    float* ua    = repr  + (size_t)BB*SS*2*HH;   // 8192*12
    float* wa    = ua    + (size_t)BB*SS*AA;     // 8192*12
    float* ce    = wa    + (size_t)BB*SS*AA;     // 8192
    float* feats = ce    + (size_t)BB*SS;        // 8192*400
    float* WT    = feats + (size_t)BB*SS*400;    // 2*24*400

    k_prep<<<(BB * SS) / 16, 256, 0, stream>>>(words, pos, morph, wtab, ptab,
                                               Wxf, Wxb, feats, WT);
    k_xg<<<256, 256, 0, stream>>>(feats, WT, bf, bb, xgf, xgb);
    k_lstm<<<BB * 2, 64, 0, stream>>>(xgf, xgb, Whf, Whb, repr);
    k_uawa<<<(BB * SS) / 256, 256, 0, stream>>>(repr, Wu, bu, Ww, bw, ua, wa);
    k_score<<<BB * SS, 256, 0, stream>>>(ua, wa, v, heads, out, ce);
    k_loss<<<1, 256, 0, stream>>>(ce, out);
}

// Round 9
// 73.798 us; speedup vs baseline: 1.2455x; 1.2455x over previous
//
#include <hip/hip_runtime.h>
#include <hip/hip_bf16.h>

// Problem constants
#define BB 32
#define SS 256
#define DD 300
#define PDD 32
#define MM 66
#define FF 398      // D + PD + M
#define HH 6
#define G4 24       // 4*H
#define AA 12
#define L2E 1.4426950408889634f

__device__ __forceinline__ float fast_rcp(float x) { return __builtin_amdgcn_rcpf(x); }
__device__ __forceinline__ float fast_tanh(float x) {
    return 1.f - 2.f * fast_rcp(__expf(2.f * x) + 1.f);
}
__device__ __forceinline__ float bcast_lane(float x, int l) {
    return __int_as_float(__builtin_amdgcn_readlane(__float_as_int(x), l));
}
template<int CTRL>
__device__ __forceinline__ float quad_bcast(float v) {
    // DPP quad_perm broadcast: CTRL = 0 / 85 / 170 / 255 -> quad lane 0/1/2/3
    return __int_as_float(__builtin_amdgcn_mov_dpp(__float_as_int(v), CTRL, 0xf, 0xf, true));
}

// -------------------------------------------------------------------------
// Kernel 1 (v5): fused embed+concat+projection, single kernel.
// Block = 32 positions, 256 thr, grid 256 (1 block/CU). Feats staged ONCE,
// transposed sF[q][pad 33] (conflict-free hot reads); ALL of W in LDS
// (sW[48][400]); wave = 32 pos x 2 col-groups. Hot loop: 1 feats b128 +
// 6 near-uniform W b128 + 24 fma per q -> 24 fma per per-lane LDS read.
// Epilogue folds bias + the lstm's +-log2e gate prescale (col group ==
// one gate type -> wave-uniform scale).
// -------------------------------------------------------------------------
#define EPB 32
__global__ __launch_bounds__(256) void k_embed_proj(
    const int* __restrict__ words, const int* __restrict__ pos,
    const float* __restrict__ morph, const float* __restrict__ wtab,
    const float* __restrict__ ptab,
    const float* __restrict__ Wxf, const float* __restrict__ bfv,
    const float* __restrict__ Wxb, const float* __restrict__ bbv,
    float* __restrict__ xgf, float* __restrict__ xgb)
{
    __shared__ float4 sF[100][33];      // 52.8 KB, sF[q][p] = feats[p][4q..4q+3]
    __shared__ float4 sW[48 * 100];     // 76.8 KB, sW[col*100+q]
    int t  = threadIdx.x;
    int p0 = blockIdx.x * EPB;

    // word part: q 0..74 (coalesced row reads)
    for (int idx = t; idx < EPB * 75; idx += 256) {
        int p = idx / 75, q = idx % 75;
        sF[q][p] = *(const float4*)(wtab + (size_t)words[p0 + p] * DD + 4 * q);
    }
    // pos part: q 75..82
    {
        int idx = t;                    // EPB*8 = 256 exactly
        int p = idx / 8, q = idx % 8;
        sF[75 + q][p] = *(const float4*)(ptab + pos[p0 + p] * PDD + 4 * q);
    }
    // morph part: q 83..99 (float2 granularity; q99 = 2 morph + 2 zero pad)
    for (int idx = t; idx < EPB * 17; idx += 256) {
        int p = idx / 17, mq = idx % 17;
        const float2* ms = (const float2*)(morph + (size_t)(p0 + p) * MM);
        float2 lo = ms[2 * mq];
        float2 hi = (mq < 16) ? ms[2 * mq + 1] : make_float2(0.f, 0.f);
        sF[83 + mq][p] = make_float4(lo.x, lo.y, hi.x, hi.y);
    }
    // W: coalesced source reads (idx = k*24+j); cols 0-23 fwd, 24-47 bwd
    {
        float* sWf = (float*)sW;
        for (int idx = t; idx < FF * G4; idx += 256) {
            int k = idx / G4, j = idx % G4;
            sWf[j * 400 + k]        = Wxf[idx];
            sWf[(24 + j) * 400 + k] = Wxb[idx];
        }
        if (t < 2 * G4) {               // zero pad k = 398,399
            int j = t >> 1, k = 398 + (t & 1);
            sWf[j * 400 + k] = 0.f; sWf[(24 + j) * 400 + k] = 0.f;
        }
    }
    __syncthreads();

    int lane = t & 63, w = t >> 6;
    int p    = lane & 31;               // position within block
    int cg   = w * 2 + (lane >> 5);     // 0..7 col group
    int dir  = cg >> 2;
    int tg   = cg & 3;                  // gate-type group (keras cols tg*6..+5)
    int j0   = tg * 6;
    const float4* wc = sW + (dir * 24 + j0) * 100;

    float a0 = 0.f, a1 = 0.f, a2 = 0.f, a3 = 0.f, a4 = 0.f, a5 = 0.f;
    #pragma unroll 4
    for (int q = 0; q < 100; ++q) {
        float4 f = sF[q][p];
        float4 w0 = wc[0 * 100 + q], w1 = wc[1 * 100 + q], w2 = wc[2 * 100 + q];
        float4 w3 = wc[3 * 100 + q], w4 = wc[4 * 100 + q], w5 = wc[5 * 100 + q];
        a0 = fmaf(f.x, w0.x, a0); a0 = fmaf(f.y, w0.y, a0);
        a0 = fmaf(f.z, w0.z, a0); a0 = fmaf(f.w, w0.w, a0);
        a1 = fmaf(f.x, w1.x, a1); a1 = fmaf(f.y, w1.y, a1);
        a1 = fmaf(f.z, w1.z, a1); a1 = fmaf(f.w, w1.w, a1);
        a2 = fmaf(f.x, w2.x, a2); a2 = fmaf(f.y, w2.y, a2);
        a2 = fmaf(f.z, w2.z, a2); a2 = fmaf(f.w, w2.w, a2);
        a3 = fmaf(f.x, w3.x, a3); a3 = fmaf(f.y, w3.y, a3);
        a3 = fmaf(f.z, w3.z, a3); a3 = fmaf(f.w, w3.w, a3);
        a4 = fmaf(f.x, w4.x, a4); a4 = fmaf(f.y, w4.y, a4);
        a4 = fmaf(f.z, w4.z, a4); a4 = fmaf(f.w, w4.w, a4);
        a5 = fmaf(f.x, w5.x, a5); a5 = fmaf(f.y, w5.y, a5);
        a5 = fmaf(f.z, w5.z, a5); a5 = fmaf(f.w, w5.w, a5);
    }

    // epilogue: bias + lstm prescale (wave-uniform per col group)
    float kk = (tg == 2) ? 2.f * L2E : -L2E;
    const float* bias = dir ? bbv : bfv;
    float* o = (dir ? xgb : xgf) + (size_t)(p0 + p) * G4 + j0;
    o[0] = (a0 + bias[j0 + 0]) * kk; o[1] = (a1 + bias[j0 + 1]) * kk;
    o[2] = (a2 + bias[j0 + 2]) * kk; o[3] = (a3 + bias[j0 + 3]) * kk;
    o[4] = (a4 + bias[j0 + 4]) * kk; o[5] = (a5 + bias[j0 + 5]) * kk;
}

// -------------------------------------------------------------------------
// Kernel 2 (v9): LSTM recurrence, gate-lane layout with DPP quad gathers.
// xg arrives PRE-SCALED (embed epilogue), so staging is a pure float4 copy
// (rows reversed for bwd). Lane l owns gate g=l%24: cell=g>>2, type=g&3,
// keras col j = type*6+cell. Cell update via 4 register-file DPP quad
// broadcasts; h broadcast via readlane; 4-slot rotating LDS prefetch.
// -------------------------------------------------------------------------
__global__ __launch_bounds__(64) void k_lstm(
    const float* __restrict__ xgf, const float* __restrict__ xgb,
    const float* __restrict__ Whf, const float* __restrict__ Whb,
    float* __restrict__ repr)
{
    __shared__ float sxg[(SS + 8) * G4];    // 8 zero guard rows
    __shared__ float hbuf[SS * HH];
    int blk = blockIdx.x;                   // 0..63
    int dir = blk >> 5;
    int b   = blk & 31;
    int lane = threadIdx.x;

    const float* xg = (dir ? xgb : xgf) + (size_t)b * SS * G4;
    const float* Wh = dir ? Whb : Whf;

    // stage xg -> LDS (pure copy; reverse rows for bwd); zero guard rows
    {
        const float4* src = (const float4*)xg;
        float4* dst = (float4*)sxg;
        #pragma unroll
        for (int u = 0; u < 24; ++u) {
            int d = lane + u * 64;          // float4 index 0..1535
            int row = d / 6, c4 = d - row * 6;
            int drow = dir ? (SS - 1 - row) : row;
            dst[drow * 6 + c4] = src[d];
        }
        for (int g2 = lane; g2 < 8 * G4; g2 += 64) sxg[SS * G4 + g2] = 0.f;
    }

    int g    = lane % G4;                   // gate slot 0..23
    int cell = g >> 2;                      // 0..5
    int type = g & 3;                       // 0=i 1=f 2=c 3=o
    int j    = type * HH + cell;            // keras column

    float kk = (type == 2) ? 2.f * L2E : -L2E;
    float wh[HH];
    #pragma unroll
    for (int m = 0; m < HH; ++m) wh[m] = Wh[m * G4 + j] * kk;
    float Bc = (type == 2) ? 1.f : 0.f;
    float Ac = (type == 2) ? -1.f : 1.f;

    float sh[HH];
    #pragma unroll
    for (int m = 0; m < HH; ++m) sh[m] = 0.f;
    float c = 0.f;
    bool wr = (lane < G4) && ((lane & 3) == 0);
    __syncthreads();

    const float* xb = sxg + j;

    // 4-slot rotating register prefetch (1 ds_read per step)
    float pg[4];
    #pragma unroll
    for (int sl = 0; sl < 4; ++sl) pg[sl] = xb[sl * G4];

    #pragma unroll 1
    for (int t = 0; t < SS; t += 4) {
        #pragma unroll
        for (int sl = 0; sl < 4; ++sl) {
            float x = pg[sl];
            pg[sl] = xb[(t + 4 + sl) * G4];      // guard rows cover the tail

            // depth-4 scaled dot: x = kk*(xg_j + sum_m h_m Wh[m][j])
            float aa  = fmaf(sh[1], wh[1], fmaf(sh[0], wh[0], x));
            float bb2 = fmaf(sh[3], wh[3], sh[2] * wh[2]);
            float cc2 = fmaf(sh[5], wh[5], sh[4] * wh[4]);
            x = (aa + bb2) + cc2;

            float e   = __builtin_amdgcn_exp2f(x);
            float val = fmaf(Bc, e, Ac) * fast_rcp(1.f + e);

            // register-file gather of this cell's gates (quad_perm DPP)
            float vi = quad_bcast<0>(val);
            float vf = quad_bcast<85>(val);
            float vc = quad_bcast<170>(val);
            float vo = quad_bcast<255>(val);

            c = fmaf(vf, c, vi * vc);
            float ec = __builtin_amdgcn_exp2f(c * (2.f * L2E));
            float h  = (ec - 1.f) * fast_rcp(ec + 1.f) * vo;

            if (wr) hbuf[(t + sl) * HH + cell] = h;
            #pragma unroll
            for (int m = 0; m < HH; ++m) sh[m] = bcast_lane(h, 4 * m);
        }
    }
    __syncthreads();

    // coalesced copy out (undo time order for bwd)
    #pragma unroll
    for (int u = 0; u < (SS * HH) / 64; ++u) {
        int idx = lane + u * 64;
        int tt = idx / 6, cc = idx - tt * 6;
        int s = dir ? (SS - 1 - tt) : tt;
        repr[((size_t)b * SS + s) * (2 * HH) + dir * HH + cc] = hbuf[idx];
    }
}

// -------------------------------------------------------------------------
// Kernel 3: ua = repr@Wu+bu ; wa = repr@Ww+bw. One thread per (b,s).
// -------------------------------------------------------------------------
__global__ __launch_bounds__(256) void k_uawa(
    const float* __restrict__ repr,
    const float* __restrict__ Wu, const float* __restrict__ bu,
    const float* __restrict__ Ww, const float* __restrict__ bw,
    float* __restrict__ ua, float* __restrict__ wa)
{
    int bs = blockIdx.x * blockDim.x + threadIdx.x;   // 0..8191
    float r[AA];
    #pragma unroll
    for (int e = 0; e < AA; ++e) r[e] = repr[(size_t)bs * AA + e];
    #pragma unroll
    for (int d = 0; d < AA; ++d) {
        float au = bu[d], aw = bw[d];
        #pragma unroll
        for (int e = 0; e < AA; ++e) {
            au = fmaf(r[e], Wu[e * AA + d], au);
            aw = fmaf(r[e], Ww[e * AA + d], aw);
        }
        ua[(size_t)bs * AA + d] = au;
        wa[(size_t)bs * AA + d] = aw;
    }
}

// -------------------------------------------------------------------------
// Kernel 4: arc scores + sum-exp + CE partials + exp table.
// -------------------------------------------------------------------------
__global__ __launch_bounds__(256) void k_score(
    const float* __restrict__ ua, const float* __restrict__ wa,
    const float* __restrict__ v, const int* __restrict__ heads,
    float* __restrict__ out, float* __restrict__ ce)
{
    int bi = blockIdx.x;            // b*S + i
    int i  = bi & 255;
    int j  = threadIdx.x;

    __shared__ float swa[AA], sv[AA];
    if (j < AA) { swa[j] = wa[(size_t)bi * AA + j]; sv[j] = v[j]; }
    __syncthreads();

    const float* uj = ua + ((size_t)(bi & ~255) + j) * AA;
    float s = 0.f;
    #pragma unroll
    for (int d = 0; d < AA; ++d) s = fmaf(sv[d], fast_tanh(uj[d] + swa[d]), s);
    if (j == i) s = -10000.f;

    float e = __expf(s);
    if (i >= 1)
        out[1 + (((size_t)(i - 1) * BB + (bi >> 8)) * SS + j)] = e;

    float r = e;
    #pragma unroll
    for (int off = 32; off > 0; off >>= 1) r += __shfl_xor(r, off, 64);
    __shared__ float part[4];
    if ((j & 63) == 0) part[j >> 6] = r;
    __syncthreads();
    float tot = part[0] + part[1] + part[2] + part[3];

    if (j == heads[bi])
        ce[bi] = (i >= 1) ? (__logf(tot) - s) : 0.f;
}

// -------------------------------------------------------------------------
// Kernel 5: deterministic loss reduction: sum(ce)/B into out[0].
// -------------------------------------------------------------------------
__global__ __launch_bounds__(256) void k_loss(const float* __restrict__ ce,
                                              float* __restrict__ out)
{
    __shared__ float red[256];
    int t = threadIdx.x;
    float a = 0.f;
    for (int k = t; k < BB * SS; k += 256) a += ce[k];
    red[t] = a; __syncthreads();
    for (int off = 128; off > 0; off >>= 1) {
        if (t < off) red[t] += red[t + off];
        __syncthreads();
    }
    if (t == 0) out[0] = red[0] * (1.f / BB);
}

extern "C" void kernel_launch(void* const* d_in, const int* in_sizes, int n_in,
                              void* d_out, int out_size, void* d_ws, size_t ws_size,
                              hipStream_t stream)
{
    const int*   words = (const int*)  d_in[0];
    const int*   pos   = (const int*)  d_in[1];
    const float* morph = (const float*)d_in[2];
    const int*   heads = (const int*)  d_in[3];
    const float* wtab  = (const float*)d_in[4];
    const float* ptab  = (const float*)d_in[5];
    const float* Wxf   = (const float*)d_in[6];
    const float* Whf   = (const float*)d_in[7];
    const float* bf    = (const float*)d_in[8];
    const float* Wxb   = (const float*)d_in[9];
    const float* Whb   = (const float*)d_in[10];
    const float* bb    = (const float*)d_in[11];
    const float* Wu    = (const float*)d_in[12];
    const float* bu    = (const float*)d_in[13];
    const float* Ww    = (const float*)d_in[14];
    const float* bw    = (const float*)d_in[15];
    const float* v     = (const float*)d_in[16];
    float* out = (float*)d_out;

    // workspace layout (floats)
    float* xgf   = (float*)d_ws;                 // 8192*24 (prescaled)
    float* xgb   = xgf   + (size_t)BB*SS*G4;     // 8192*24 (prescaled)
    float* repr  = xgb   + (size_t)BB*SS*G4;     // 8192*12
    float* ua    = repr  + (size_t)BB*SS*2*HH;   // 8192*12
    float* wa    = ua    + (size_t)BB*SS*AA;     // 8192*12
    float* ce    = wa    + (size_t)BB*SS*AA;     // 8192

    k_embed_proj<<<(BB * SS) / EPB, 256, 0, stream>>>(words, pos, morph, wtab, ptab,
                                                      Wxf, bf, Wxb, bb, xgf, xgb);
    k_lstm<<<BB * 2, 64, 0, stream>>>(xgf, xgb, Whf, Whb, repr);
    k_uawa<<<(BB * SS) / 256, 256, 0, stream>>>(repr, Wu, bu, Ww, bw, ua, wa);
    k_score<<<BB * SS, 256, 0, stream>>>(ua, wa, v, heads, out, ce);
    k_loss<<<1, 256, 0, stream>>>(ce, out);
}